// Round 1
// baseline (167.804 us; speedup 1.0000x reference)
//
#include <hip/hip_runtime.h>
#include <cmath>

// Problem: B=64, S=2048, H=1024, fp32.
// scores[b,s] = <lstm[b,s,:], hidden[b,:]>; softmax over s;
// attn[b,h] = sum_s w[b,s] lstm[b,s,h]; out = [hidden,attn] @ W^T + bias.
//
// lstm_output = 512 MiB >> everything else -> HBM-bound. Single-pass online
// softmax reads it exactly once (vs 2x for a naive scores-then-sum scheme).

namespace {
constexpr int B = 64;
constexpr int S = 2048;
constexpr int H = 1024;
constexpr int NSPLIT = 16;                 // S-chunks per batch -> 1024 blocks
constexpr int CHUNK = S / NSPLIT;          // 128 rows per block
constexpr int PSTRIDE = H + 4;             // floats per partial record (16B aligned)
// ws layout: [B*NSPLIT records of PSTRIDE floats: acc[1024], m, l, pad]
//            then attn[B*H] floats
constexpr size_t ATTN_OFF = (size_t)B * NSPLIT * PSTRIDE;  // in floats
}

// ---------------- Pass 1: fused scores + online softmax + weighted sum ------
__global__ __launch_bounds__(256) void attn_pass1(
    const float* __restrict__ lstm,
    const float* __restrict__ hidden,
    float* __restrict__ ws)
{
    const int c    = blockIdx.x;        // S-chunk
    const int b    = blockIdx.y;        // batch
    const int tid  = threadIdx.x;
    const int w    = tid >> 6;          // wave 0..3
    const int lane = tid & 63;

    // hidden fragment: lane holds float4s at positions lane + 64*j (j=0..3)
    const float4* hid4 = reinterpret_cast<const float4*>(hidden + (size_t)b * H);
    float4 hv[4];
#pragma unroll
    for (int j = 0; j < 4; ++j) hv[j] = hid4[lane + 64 * j];

    float m = -INFINITY;
    float l = 0.0f;
    float4 acc[4];
#pragma unroll
    for (int j = 0; j < 4; ++j) acc[j] = make_float4(0.f, 0.f, 0.f, 0.f);

    const int s0 = c * CHUNK;
    // waves interleave rows: wave w takes rows s0+w, s0+w+4, ... (32 rows)
    for (int s = s0 + w; s < s0 + CHUNK; s += 4) {
        const float4* row4 =
            reinterpret_cast<const float4*>(lstm + ((size_t)b * S + s) * H);
        float4 r[4];
#pragma unroll
        for (int j = 0; j < 4; ++j) r[j] = row4[lane + 64 * j];  // 64B/lane, coalesced

        // dot(row, hidden): 16 FMAs per lane, then wave butterfly reduce
        float d = 0.0f;
#pragma unroll
        for (int j = 0; j < 4; ++j) {
            d = fmaf(r[j].x, hv[j].x, d);
            d = fmaf(r[j].y, hv[j].y, d);
            d = fmaf(r[j].z, hv[j].z, d);
            d = fmaf(r[j].w, hv[j].w, d);
        }
#pragma unroll
        for (int off = 32; off >= 1; off >>= 1) d += __shfl_xor(d, off);

        // online softmax update (d is wave-uniform after butterfly)
        const float nm = fmaxf(m, d);
        const float sc = __expf(m - nm);   // exp(-inf)=0 handles first row
        const float p  = __expf(d - nm);
        l = l * sc + p;
#pragma unroll
        for (int j = 0; j < 4; ++j) {
            acc[j].x = fmaf(acc[j].x, sc, p * r[j].x);
            acc[j].y = fmaf(acc[j].y, sc, p * r[j].y);
            acc[j].z = fmaf(acc[j].z, sc, p * r[j].z);
            acc[j].w = fmaf(acc[j].w, sc, p * r[j].w);
        }
        m = nm;
    }

    // ---- combine the 4 waves of this block ----
    __shared__ float red_m[4];
    __shared__ float red_l[4];
    __shared__ float4 accbuf[4 * 256];   // 16 KiB

    if (lane == 0) { red_m[w] = m; red_l[w] = l; }
    __syncthreads();

    const float M = fmaxf(fmaxf(red_m[0], red_m[1]), fmaxf(red_m[2], red_m[3]));
    const float sc = __expf(m - M);      // per-wave rescale to block max
#pragma unroll
    for (int j = 0; j < 4; ++j) {
        float4 a = acc[j];
        accbuf[w * 256 + lane + 64 * j] =
            make_float4(a.x * sc, a.y * sc, a.z * sc, a.w * sc);
    }
    __syncthreads();

    const float L = red_l[0] * __expf(red_m[0] - M)
                  + red_l[1] * __expf(red_m[1] - M)
                  + red_l[2] * __expf(red_m[2] - M)
                  + red_l[3] * __expf(red_m[3] - M);

    float* part = ws + (size_t)(b * NSPLIT + c) * PSTRIDE;
    float4 s4 = accbuf[tid];
    {
        float4 t1 = accbuf[256 + tid];
        float4 t2 = accbuf[512 + tid];
        float4 t3 = accbuf[768 + tid];
        s4.x += t1.x + t2.x + t3.x;
        s4.y += t1.y + t2.y + t3.y;
        s4.z += t1.z + t2.z + t3.z;
        s4.w += t1.w + t2.w + t3.w;
    }
    reinterpret_cast<float4*>(part)[tid] = s4;   // unnormalized acc
    if (tid == 0) { part[H] = M; part[H + 1] = L; }
}

// ---------------- Pass 2: merge NSPLIT partials per batch -------------------
__global__ __launch_bounds__(256) void attn_pass2(float* __restrict__ ws)
{
    const int b   = blockIdx.x;
    const int tid = threadIdx.x;

    __shared__ float sm[NSPLIT];
    __shared__ float sl[NSPLIT];
    if (tid < NSPLIT) {
        const float* part = ws + (size_t)(b * NSPLIT + tid) * PSTRIDE;
        sm[tid] = part[H];
        sl[tid] = part[H + 1];
    }
    __syncthreads();

    float M = -INFINITY;
#pragma unroll
    for (int i = 0; i < NSPLIT; ++i) M = fmaxf(M, sm[i]);

    float f[NSPLIT];
    float L = 0.0f;
#pragma unroll
    for (int i = 0; i < NSPLIT; ++i) {
        f[i] = __expf(sm[i] - M);
        L = fmaf(sl[i], f[i], L);
    }
    const float inv = 1.0f / L;

    float4 a = make_float4(0.f, 0.f, 0.f, 0.f);
#pragma unroll
    for (int i = 0; i < NSPLIT; ++i) {
        const float4* p4 = reinterpret_cast<const float4*>(
            ws + (size_t)(b * NSPLIT + i) * PSTRIDE);
        float4 v = p4[tid];
        a.x = fmaf(v.x, f[i], a.x);
        a.y = fmaf(v.y, f[i], a.y);
        a.z = fmaf(v.z, f[i], a.z);
        a.w = fmaf(v.w, f[i], a.w);
    }
    float4* attn4 = reinterpret_cast<float4*>(ws + ATTN_OFF) + (size_t)b * (H / 4);
    attn4[tid] = make_float4(a.x * inv, a.y * inv, a.z * inv, a.w * inv);
}

// ---------------- Pass 3: out = [hidden, attn] @ W^T + bias -----------------
// Block: 4 output features x 64 batches. W rows staged in LDS (broadcast).
__global__ __launch_bounds__(256) void attn_pass3(
    const float* __restrict__ hidden,
    const float* __restrict__ W,       // [H, 2H] row-major
    const float* __restrict__ bias,
    const float* __restrict__ ws,
    float* __restrict__ out)
{
    __shared__ float4 Wt[4 * 512];     // 4 rows x 2048 floats = 32 KiB
    const int tid = threadIdx.x;
    const int ob  = blockIdx.x * 4;

    const float4* W4 = reinterpret_cast<const float4*>(W + (size_t)ob * (2 * H));
#pragma unroll
    for (int j = 0; j < 8; ++j) Wt[tid + 256 * j] = W4[tid + 256 * j];
    __syncthreads();

    const int b  = tid & 63;           // lane == batch -> LDS reads broadcast
    const int ol = tid >> 6;
    const int o  = ob + ol;

    const float4* hid4 = reinterpret_cast<const float4*>(hidden + (size_t)b * H);
    const float4* att4 = reinterpret_cast<const float4*>(ws + ATTN_OFF) + (size_t)b * (H / 4);

    float acc = bias[o];
#pragma unroll 4
    for (int k = 0; k < H / 4; ++k) {
        float4 h = hid4[k];
        float4 wv = Wt[ol * 512 + k];
        acc = fmaf(h.x, wv.x, acc);
        acc = fmaf(h.y, wv.y, acc);
        acc = fmaf(h.z, wv.z, acc);
        acc = fmaf(h.w, wv.w, acc);
    }
#pragma unroll 4
    for (int k = 0; k < H / 4; ++k) {
        float4 a = att4[k];
        float4 wv = Wt[ol * 512 + 256 + k];
        acc = fmaf(a.x, wv.x, acc);
        acc = fmaf(a.y, wv.y, acc);
        acc = fmaf(a.z, wv.z, acc);
        acc = fmaf(a.w, wv.w, acc);
    }
    out[(size_t)b * H + o] = acc;
}

extern "C" void kernel_launch(void* const* d_in, const int* in_sizes, int n_in,
                              void* d_out, int out_size, void* d_ws, size_t ws_size,
                              hipStream_t stream)
{
    const float* lstm   = (const float*)d_in[0];  // [B,S,H]
    const float* hidden = (const float*)d_in[1];  // [B,H]
    const float* W      = (const float*)d_in[2];  // [H,2H]
    const float* bias   = (const float*)d_in[3];  // [H]
    float* out = (float*)d_out;                   // [B,H]
    float* ws  = (float*)d_ws;                    // needs ~4.5 MB

    attn_pass1<<<dim3(NSPLIT, B), 256, 0, stream>>>(lstm, hidden, ws);
    attn_pass2<<<dim3(B), 256, 0, stream>>>(ws);
    attn_pass3<<<dim3(H / 4), 256, 0, stream>>>(hidden, W, bias, ws, out);
}